// Round 3
// baseline (89.545 us; speedup 1.0000x reference)
//
#include <hip/hip_runtime.h>

// GCNnet: reference output = softmax(z, axis=-1) where z has shape (G, 1).
// Softmax over a length-1 axis is identically 1.0 regardless of inputs,
// so the whole GCN/pool/MLP pipeline is dead code w.r.t. the output.
// Optimal kernel: fill d_out (128 floats) with 1.0f.

__global__ void GCNnet_ones_kernel(float* __restrict__ out, int n) {
    int i = blockIdx.x * blockDim.x + threadIdx.x;
    if (i < n) out[i] = 1.0f;
}

extern "C" void kernel_launch(void* const* d_in, const int* in_sizes, int n_in,
                              void* d_out, int out_size, void* d_ws, size_t ws_size,
                              hipStream_t stream) {
    (void)d_in; (void)in_sizes; (void)n_in; (void)d_ws; (void)ws_size;
    float* out = (float*)d_out;
    int threads = 128;
    int blocks = (out_size + threads - 1) / threads;  // out_size = 128 -> 1 block
    GCNnet_ones_kernel<<<blocks, threads, 0, stream>>>(out, out_size);
}